// Round 13
// baseline (133.872 us; speedup 1.0000x reference)
//
#include <hip/hip_runtime.h>
#include <hip/hip_bf16.h>
#include <math.h>

#define H 64
#define W 64
#define CIN 128
#define COUT 128
#define BATCH 8
#define NPIX (H*W)      // 4096
#define PXT 32          // pixels per k_deform block
#define AP  136         // vs pitch in bf16
#define VSZ (PXT*AP)    // one vs buffer in shorts (4352)

typedef __attribute__((ext_vector_type(8))) short bf16x8;
typedef __attribute__((ext_vector_type(4))) float f32x4;
typedef __attribute__((ext_vector_type(16))) float f32x16;

static __device__ inline short f2bf(float f) {
  union { float f; unsigned u; } v; v.f = f;
  unsigned r = v.u + 0x7FFF + ((v.u >> 16) & 1);   // RNE
  return (short)(r >> 16);
}
static __device__ inline float bf_lo(unsigned u) {
  union { unsigned u; float f; } v; v.u = u << 16; return v.f;
}
static __device__ inline float bf_hi(unsigned u) {
  union { unsigned u; float f; } v; v.u = u & 0xffff0000u; return v.f;
}

// ---------------------------------------------------------------------------
// Kernel 1 (fused prep): [0,2048) transpose NCHW->BHWC bf16 (R13: short4
// vectorized stores); [2048,2192) pack wOMs32; [2192,2768) pack wAs32.
// 32x32x16 A-frag layout: A[m=lane&31][k=(lane>>5)*8+j] (verified R11).
// ---------------------------------------------------------------------------
__global__ __launch_bounds__(256) void k_prep(const float* __restrict__ x,
    short* __restrict__ xbh,
    const float* __restrict__ w_off, const float* __restrict__ w_mod,
    short* __restrict__ wOMs, const float* __restrict__ w_reg,
    short* __restrict__ wAs) {
  __shared__ float tile[32][65];
  int blk = blockIdx.x;
  int t = threadIdx.x;
  if (blk < 2048) {                       // --- transpose ---
    int cg = blk & 3, y = (blk >> 2) & 63, b = blk >> 8;
#pragma unroll
    for (int j = 0; j < 8; ++j) {
      int idx = t + j * 256;
      int ci = idx >> 6, xi = idx & 63;
      tile[ci][xi] = x[(((b * CIN + cg * 32 + ci) * H + y) * W) + xi];
    }
    __syncthreads();
#pragma unroll
    for (int i = 0; i < 2; ++i) {         // 512 items = 64 xi x 8 cig
      int idx = t + i * 256;
      int xi = idx >> 3, cig = idx & 7;
      float f0 = tile[cig * 4 + 0][xi];
      float f1 = tile[cig * 4 + 1][xi];
      float f2 = tile[cig * 4 + 2][xi];
      float f3 = tile[cig * 4 + 3][xi];
      __hip_bfloat162 h01 = __float22bfloat162_rn(make_float2(f0, f1));
      __hip_bfloat162 h23 = __float22bfloat162_rn(make_float2(f2, f3));
      uint2 pk;
      pk.x = *(unsigned*)&h01; pk.y = *(unsigned*)&h23;
      *(uint2*)&xbh[((b * H + y) * W + xi) * CIN + cg * 32 + cig * 4] = pk;
    }
  } else if (blk < 2048 + 144) {          // --- wOMs32 pack ---
    int e = (blk - 2048) * 256 + t;       // tap*4096 + oc*128 + c  (36864)
    int tap = e >> 12, oc = (e >> 7) & 31, c = e & 127;
    float v = 0.f;
    if (oc < 18)      v = w_off[(oc * 128 + c) * 9 + tap];
    else if (oc < 27) v = w_mod[((oc - 18) * 128 + c) * 9 + tap];
    int kstep = c >> 4, g = (c >> 3) & 1, j = c & 7;
    int lane = g * 32 + oc;
    int o = ((tap * 8 + kstep) * 64 + lane) * 8 + j;
    wOMs[o] = f2bf(v);
  } else {                                // --- wAs32 pack ---
    int e = (blk - 2192) * 256 + t;       // tap*16384 + oc*128 + c
    int tap = e >> 14, oc = (e >> 7) & 127, c = e & 127;
    int kstep = c >> 4, g = (c >> 3) & 1, j = c & 7;
    int ms = oc >> 5, m = oc & 31;
    int lane = g * 32 + m;
    int o = (((tap * 8 + kstep) * 4 + ms) * 64 + lane) * 8 + j;
    wAs[o] = f2bf(w_reg[(oc * 128 + c) * 9 + tap]);
  }
}

// ---------------------------------------------------------------------------
// Kernel 2: FUSED offset/mask + deformable conv.  512 threads, 8 waves.
// R13: phase-1 B from an XOR-swizzled LDS halo (3 rows x 34 cols x 128 ch,
// zero-padded) staged in ~26 coalesced VMEM instrs — replaces 224 im2col
// gathers; partials reduced via LDS atomicAdd into redA (3.5 KB, replaces
// the 31 KB red).  Phase 2 reverted to the R11 (non-pipelined) structure.
// 32x32x16 layouts: A[m=lane&31][k=(lane>>5)*8+j],
//   C/D row=(r&3)+8*(r>>2)+4*(lane>>5), col=lane&31 [m74/m101, R11-verified].
// LDS: max(redA 3584+halo 26112, vs-dbuf 17408, redE 16896) + pw + pa = 36.6K
//   -> 4 blocks/CU at grid 1024 (32 waves/CU).
// ---------------------------------------------------------------------------
__global__ __launch_bounds__(512, 8) void k_deform(const short* __restrict__ xbh,
    const short* __restrict__ wOMs, const float* __restrict__ b_off,
    const float* __restrict__ b_mod, const short* __restrict__ wAs,
    float* __restrict__ out) {
  __shared__ __align__(16) char smem_u[29696];     // [redA|halo] / vs dbuf / redE
  __shared__ __align__(16) float  pw[PXT * 9 * 4]; // 4608 B
  __shared__ __align__(16) ushort pa4[PXT * 9 * 4];// 2304 B (pixel-linear)
  float* redA = (float*)smem_u;                    // 27 x 33 floats (3564 B)
  short* halo = (short*)(smem_u + 3584);           // 3*34*128 shorts (26112 B)
  short* vs   = (short*)smem_u;                    // phase 2: 2 x 4352 shorts
  float* redE = (float*)smem_u;                    // epilogue: 4 x 32 x 33

  int blk = blockIdx.x;
  int b = blk & 7, tile = blk >> 3;               // XCD swizzle
  int pix0 = tile * PXT;
  int y0r = pix0 >> 6, x0r = pix0 & 63;           // block row, row-half base
  int t = threadIdx.x;
  int lane = t & 63;
  int wv = t >> 6;                                // 0..7
  int n32 = lane & 31, g = lane >> 5;

  const short* xbB = xbh + (size_t)b * NPIX * CIN;

  // ===== stage halo (zero-padded, XOR-swizzled chunks) + zero redA =====
  for (int i = t; i < 27 * 33; i += 512) redA[i] = 0.f;
  for (int i = t; i < 3 * 34 * 16; i += 512) {    // 1632 chunks of 16 B
    int row34 = i / 544, rem = i - row34 * 544;
    int col = rem >> 4, ck = rem & 15;
    int yy = y0r + row34 - 1, xx = x0r + col - 1;
    bf16x8 v = {};
    if ((unsigned)yy < H && (unsigned)xx < W)
      v = *(const bf16x8*)&xbB[(size_t)((yy << 6) + xx) * CIN + ck * 8];
    *(bf16x8*)&halo[((row34 * 34 + col) << 7) + ((ck ^ (col & 15)) << 3)] = v;
  }
  __syncthreads();

  // ===== Phase 1: offset/mask mini-GEMM, wave = taps {wv, wv+8} =====
  {
    f32x16 accO = {};
#pragma unroll
    for (int ti = 0; ti < 2; ++ti) {
      int tap = wv + ti * 8;
      if (tap > 8) break;                         // wave-uniform
      int dy = tap / 3 - 1, dx = tap % 3 - 1;
      int col = n32 + dx + 1;                     // 0..33
      int colbase = (((dy + 1) * 34 + col) << 7);
      int sw = col & 15;
#pragma unroll
      for (int kstep = 0; kstep < 8; ++kstep) {
        bf16x8 a = *(const bf16x8*)&wOMs[((tap * 8 + kstep) * 64 + lane) * 8];
        int ck = kstep * 2 + g;
        bf16x8 bv = *(const bf16x8*)&halo[colbase + ((ck ^ sw) << 3)];
        accO = __builtin_amdgcn_mfma_f32_32x32x16_bf16(a, bv, accO, 0, 0, 0);
      }
    }
#pragma unroll
    for (int r = 0; r < 16; ++r) {
      int row = (r & 3) + 8 * (r >> 2) + 4 * g;
      if (row < 27) atomicAdd(&redA[row * 33 + n32], accO[r]);
    }
  }
  __syncthreads();

  // ===== bias + sigmoid -> pw / pa4 (single redA read, no 8-way sum) =====
  for (int i = t; i < PXT * 9; i += 512) {        // i = p*9 + tap
    int tap = i % 9, p = i / 9;
    float dyv = b_off[2 * tap]     + redA[(2 * tap) * 33 + p];
    float dxv = b_off[2 * tap + 1] + redA[(2 * tap + 1) * 33 + p];
    float z   = b_mod[tap]         + redA[(18 + tap) * 33 + p];
    float m = 2.f / (1.f + expf(-z));
    int gp = pix0 + p;
    float py = (float)((gp >> 6) - 1 + tap / 3) + dyv;
    float pxx = (float)((gp & 63) - 1 + tap % 3) + dxv;
    float yf = floorf(py), xf = floorf(pxx);
    float wy = py - yf, wx = pxx - xf;
    int y0 = (int)yf, x0 = (int)xf;
    int y1 = y0 + 1, x1 = x0 + 1;
    float vy0 = ((unsigned)y0 < H) ? 1.f : 0.f;
    float vy1 = ((unsigned)y1 < H) ? 1.f : 0.f;
    float vx0 = ((unsigned)x0 < W) ? 1.f : 0.f;
    float vx1 = ((unsigned)x1 < W) ? 1.f : 0.f;
    int y0c = min(max(y0, 0), H - 1), y1c = min(max(y1, 0), H - 1);
    int x0c = min(max(x0, 0), W - 1), x1c = min(max(x1, 0), W - 1);
    *(float4*)&pw[i * 4] = make_float4((1.f - wy) * (1.f - wx) * m * vy0 * vx0,
                                       (1.f - wy) * wx * m * vy0 * vx1,
                                       wy * (1.f - wx) * m * vy1 * vx0,
                                       wy * wx * m * vy1 * vx1);
    pa4[i * 4 + 0] = (ushort)((y0c << 6) + x0c);
    pa4[i * 4 + 1] = (ushort)((y0c << 6) + x1c);
    pa4[i * 4 + 2] = (ushort)((y1c << 6) + x0c);
    pa4[i * 4 + 3] = (ushort)((y1c << 6) + x1c);
  }
  __syncthreads();   // pw/pa visible; redA/halo dead (vs may alias)

  // ===== Phase 2: deformable GEMM, 32x32x16, split-K (R11 structure) =====
  int ms = wv & 3, ks = wv >> 2;
  int cq = t & 15, ps = t >> 4;           // 8-ch group, pixel (0..31)
  int c0s = cq * 8;

  f32x16 acc = {};

  for (int tap = 0; tap < 9; ++tap) {
    short* vbuf = vs + (tap & 1) * VSZ;

    // --- sample: 1 px x 8 ch per thread, 4 corner gathers of 16 B ---
    {
      int idx = (ps * 9 + tap) * 4;
      float4 wq = *(const float4*)&pw[idx];
      uint4 u00 = *(const uint4*)&xbB[(int)pa4[idx]     * CIN + c0s];
      uint4 u01 = *(const uint4*)&xbB[(int)pa4[idx + 1] * CIN + c0s];
      uint4 u10 = *(const uint4*)&xbB[(int)pa4[idx + 2] * CIN + c0s];
      uint4 u11 = *(const uint4*)&xbB[(int)pa4[idx + 3] * CIN + c0s];
      uint4 packed;
#pragma unroll
      for (int j = 0; j < 4; ++j) {
        unsigned ua = ((const unsigned*)&u00)[j];
        unsigned ub = ((const unsigned*)&u01)[j];
        unsigned uc = ((const unsigned*)&u10)[j];
        unsigned ud = ((const unsigned*)&u11)[j];
        float s0 = fmaf(wq.w, bf_lo(ud), fmaf(wq.z, bf_lo(uc),
                   fmaf(wq.y, bf_lo(ub), wq.x * bf_lo(ua))));
        float s1 = fmaf(wq.w, bf_hi(ud), fmaf(wq.z, bf_hi(uc),
                   fmaf(wq.y, bf_hi(ub), wq.x * bf_hi(ua))));
        __hip_bfloat162 h2 = __float22bfloat162_rn(make_float2(s0, s1));
        ((unsigned*)&packed)[j] = *(unsigned*)&h2;
      }
      *(uint4*)&vbuf[ps * AP + c0s] = packed;
    }

    // --- A frags: 4 k-steps, contiguous 1 KB wave loads ---
    bf16x8 af[4];
#pragma unroll
    for (int i = 0; i < 4; ++i) {
      int kstep = ks * 4 + i;
      af[i] = *(const bf16x8*)&wAs[(((tap * 8 + kstep) * 4 + ms) * 64 + lane) * 8];
    }
    __syncthreads();   // vbuf visible; other buffer free for tap+1

    // --- MFMA: 4 k-steps of 32x32x16 ---
#pragma unroll
    for (int i = 0; i < 4; ++i) {
      int kstep = ks * 4 + i;
      int c0 = kstep * 16 + g * 8;
      bf16x8 bfr = *(const bf16x8*)&vbuf[n32 * AP + c0];
      acc = __builtin_amdgcn_mfma_f32_32x32x16_bf16(af[i], bfr, acc, 0, 0, 0);
    }
  }

  // ===== epilogue: split-K reduce via redE, then store =====
  __syncthreads();   // all MFMA vs-reads done before redE aliases
  if (ks == 1) {
#pragma unroll
    for (int r = 0; r < 16; ++r) {
      int row = (r & 3) + 8 * (r >> 2) + 4 * g;
      redE[ms * (32 * 33) + row * 33 + n32] = acc[r];
    }
  }
  __syncthreads();
  if (ks == 0) {
#pragma unroll
    for (int r = 0; r < 16; ++r) {
      int row = (r & 3) + 8 * (r >> 2) + 4 * g;
      float v = acc[r] + redE[ms * (32 * 33) + row * 33 + n32];
      out[(size_t)(b * COUT + ms * 32 + row) * NPIX + pix0 + n32] = v;
    }
  }
}

// ---------------------------------------------------------------------------
extern "C" void kernel_launch(void* const* d_in, const int* in_sizes, int n_in,
                              void* d_out, int out_size, void* d_ws, size_t ws_size,
                              hipStream_t stream) {
  const float* x     = (const float*)d_in[0];
  const float* w_off = (const float*)d_in[1];
  const float* b_off = (const float*)d_in[2];
  const float* w_mod = (const float*)d_in[3];
  const float* b_mod = (const float*)d_in[4];
  const float* w_reg = (const float*)d_in[5];

  short* xbh  = (short*)d_ws;              // 4,194,304 bf16 (8 MB)
  short* wAs  = xbh + 4194304;             //   147,456 bf16 (32x32 swizzled)
  short* wOMs = wAs + 147456;              //    36,864 bf16 (32x32 swizzled)
  float* out  = (float*)d_out;

  k_prep<<<dim3(2768), 256, 0, stream>>>(x, xbh, w_off, w_mod, wOMs,
                                         w_reg, wAs);
  k_deform<<<dim3(NPIX / PXT * BATCH), 512, 0, stream>>>(
      xbh, wOMs, b_off, b_mod, wAs, out);
}

// Round 14
// 111.892 us; speedup vs baseline: 1.1964x; 1.1964x over previous
//
#include <hip/hip_runtime.h>
#include <hip/hip_bf16.h>
#include <math.h>

#define H 64
#define W 64
#define CIN 128
#define COUT 128
#define BATCH 8
#define NPIX (H*W)      // 4096
#define PXT 32          // pixels per k_deform block
#define AP  136         // vs pitch in bf16
#define RP  36          // red pitch (floats)
#define VSZ (PXT*AP)    // one vs buffer in shorts (4352)

typedef __attribute__((ext_vector_type(8))) short bf16x8;
typedef __attribute__((ext_vector_type(4))) float f32x4;
typedef __attribute__((ext_vector_type(16))) float f32x16;

static __device__ inline short f2bf(float f) {
  union { float f; unsigned u; } v; v.f = f;
  unsigned r = v.u + 0x7FFF + ((v.u >> 16) & 1);   // RNE
  return (short)(r >> 16);
}
static __device__ inline float bf_lo(unsigned u) {
  union { unsigned u; float f; } v; v.u = u << 16; return v.f;
}
static __device__ inline float bf_hi(unsigned u) {
  union { unsigned u; float f; } v; v.u = u & 0xffff0000u; return v.f;
}

// ---------------------------------------------------------------------------
// Kernel 1 (fused prep): [0,2048) transpose NCHW->BHWC bf16 (R14: float4
// loads + uint2 packed stores); [2048,2192) pack wOMs32; [2192,2768) wAs32.
// 32x32x16 A-frag layout: A[m=lane&31][k=(lane>>5)*8+j] (verified R11).
// ---------------------------------------------------------------------------
__global__ __launch_bounds__(256) void k_prep(const float* __restrict__ x,
    short* __restrict__ xbh,
    const float* __restrict__ w_off, const float* __restrict__ w_mod,
    short* __restrict__ wOMs, const float* __restrict__ w_reg,
    short* __restrict__ wAs) {
  __shared__ float tile[32][65];
  int blk = blockIdx.x;
  int t = threadIdx.x;
  if (blk < 2048) {                       // --- transpose ---
    int cg = blk & 3, y = (blk >> 2) & 63, b = blk >> 8;
#pragma unroll
    for (int j = 0; j < 2; ++j) {         // 512 float4s, 2 per thread
      int f = t + j * 256;
      int ci = f >> 4, xi4 = f & 15;
      float4 v = *(const float4*)&x[(((b * CIN + cg * 32 + ci) * H + y) * W) + xi4 * 4];
      *(float4*)&tile[ci][xi4 * 4] = v;
    }
    __syncthreads();
#pragma unroll
    for (int i = 0; i < 2; ++i) {         // 512 items = 64 xi x 8 cig
      int idx = t + i * 256;
      int xi = idx >> 3, cig = idx & 7;
      float f0 = tile[cig * 4 + 0][xi];
      float f1 = tile[cig * 4 + 1][xi];
      float f2 = tile[cig * 4 + 2][xi];
      float f3 = tile[cig * 4 + 3][xi];
      __hip_bfloat162 h01 = __float22bfloat162_rn(make_float2(f0, f1));
      __hip_bfloat162 h23 = __float22bfloat162_rn(make_float2(f2, f3));
      uint2 pk;
      pk.x = *(unsigned*)&h01; pk.y = *(unsigned*)&h23;
      *(uint2*)&xbh[((b * H + y) * W + xi) * CIN + cg * 32 + cig * 4] = pk;
    }
  } else if (blk < 2048 + 144) {          // --- wOMs32 pack ---
    int e = (blk - 2048) * 256 + t;       // tap*4096 + oc*128 + c  (36864)
    int tap = e >> 12, oc = (e >> 7) & 31, c = e & 127;
    float v = 0.f;
    if (oc < 18)      v = w_off[(oc * 128 + c) * 9 + tap];
    else if (oc < 27) v = w_mod[((oc - 18) * 128 + c) * 9 + tap];
    int kstep = c >> 4, g = (c >> 3) & 1, j = c & 7;
    int lane = g * 32 + oc;
    int o = ((tap * 8 + kstep) * 64 + lane) * 8 + j;
    wOMs[o] = f2bf(v);
  } else {                                // --- wAs32 pack ---
    int e = (blk - 2192) * 256 + t;       // tap*16384 + oc*128 + c
    int tap = e >> 14, oc = (e >> 7) & 127, c = e & 127;
    int kstep = c >> 4, g = (c >> 3) & 1, j = c & 7;
    int ms = oc >> 5, m = oc & 31;
    int lane = g * 32 + m;
    int o = (((tap * 8 + kstep) * 4 + ms) * 64 + lane) * 8 + j;
    wAs[o] = f2bf(w_reg[(oc * 128 + c) * 9 + tap]);
  }
}

// ---------------------------------------------------------------------------
// Kernel 2: FUSED offset/mask + deformable conv — R11 structure verbatim
// (best measured; R12 pipeline and R13 halo both regressed it).
// 512 threads, 8 waves.  mfma_f32_32x32x16_bf16 everywhere.
//   Phase 1: wave wv = taps {wv, wv+8}; im2col B gathered per wave (no
//            intra-phase barriers — waves progress independently).
//   Phase 2: wave = (ms oc-slice, ks K-half); sample -> A-load -> barrier
//            -> MFMA per tap, dbuf vs; split-K reduced via redE at end.
// Layouts: A[m=lane&31][k=(lane>>5)*8+j] (R11 absmax-verified),
//   C/D row=(r&3)+8*(r>>2)+4*(lane>>5), col=lane&31 [m74/m101].
// ---------------------------------------------------------------------------
__global__ __launch_bounds__(512, 8) void k_deform(const short* __restrict__ xbh,
    const short* __restrict__ wOMs, const float* __restrict__ b_off,
    const float* __restrict__ b_mod, const short* __restrict__ wAs,
    float* __restrict__ out) {
  __shared__ __align__(16) char smem_u[31104];     // red | vs dbuf | redE
  __shared__ __align__(16) float  pw[PXT * 9 * 4]; // 4608 B
  __shared__ __align__(16) ushort pa4[PXT * 9 * 4];// 2304 B (pixel-linear)
  float* red  = (float*)smem_u;
  short* vs   = (short*)smem_u;
  float* redE = (float*)smem_u;

  int blk = blockIdx.x;
  int b = blk & 7, tile = blk >> 3;               // XCD swizzle
  int pix0 = tile * PXT;
  int t = threadIdx.x;
  int lane = t & 63;
  int wv = t >> 6;                                // 0..7
  int n32 = lane & 31, g = lane >> 5;

  const short* xbB = xbh + (size_t)b * NPIX * CIN;

  // ===== Phase 1: offset/mask mini-GEMM, wave = taps {wv, wv+8} =====
  {
    f32x16 accO = {};
#pragma unroll
    for (int ti = 0; ti < 2; ++ti) {
      int tap = wv + ti * 8;
      if (tap > 8) break;                         // wave-uniform
      int dy = tap / 3 - 1, dx = tap % 3 - 1;
      int gp = pix0 + n32;
      int y = (gp >> 6) + dy, x = (gp & 63) + dx;
      int ok = ((unsigned)y < H) && ((unsigned)x < W);
      int lin = ok ? ((y << 6) + x) : 0;
#pragma unroll
      for (int kstep = 0; kstep < 8; ++kstep) {
        bf16x8 a = *(const bf16x8*)&wOMs[((tap * 8 + kstep) * 64 + lane) * 8];
        int c0 = kstep * 16 + g * 8;
        bf16x8 bv = *(const bf16x8*)&xbB[(size_t)lin * CIN + c0];
        if (!ok) bv = (bf16x8){};
        accO = __builtin_amdgcn_mfma_f32_32x32x16_bf16(a, bv, accO, 0, 0, 0);
      }
    }
#pragma unroll
    for (int r = 0; r < 16; ++r) {
      int row = (r & 3) + 8 * (r >> 2) + 4 * g;
      if (row < 27) red[wv * (27 * RP) + row * RP + n32] = accO[r];
    }
  }
  __syncthreads();

  // ===== reduce 8 partials + bias + sigmoid -> pw / pa4 =====
  for (int i = t; i < PXT * 9; i += 512) {        // i = p*9 + tap
    int tap = i % 9, p = i / 9;
    float dyv = b_off[2 * tap], dxv = b_off[2 * tap + 1], z = b_mod[tap];
#pragma unroll
    for (int w = 0; w < 8; ++w) {
      const float* rw = red + w * (27 * RP);
      dyv += rw[(2 * tap) * RP + p];
      dxv += rw[(2 * tap + 1) * RP + p];
      z   += rw[(18 + tap) * RP + p];
    }
    float m = 2.f / (1.f + expf(-z));
    int gp = pix0 + p;
    float py = (float)((gp >> 6) - 1 + tap / 3) + dyv;
    float pxx = (float)((gp & 63) - 1 + tap % 3) + dxv;
    float yf = floorf(py), xf = floorf(pxx);
    float wy = py - yf, wx = pxx - xf;
    int y0 = (int)yf, x0 = (int)xf;
    int y1 = y0 + 1, x1 = x0 + 1;
    float vy0 = ((unsigned)y0 < H) ? 1.f : 0.f;
    float vy1 = ((unsigned)y1 < H) ? 1.f : 0.f;
    float vx0 = ((unsigned)x0 < W) ? 1.f : 0.f;
    float vx1 = ((unsigned)x1 < W) ? 1.f : 0.f;
    int y0c = min(max(y0, 0), H - 1), y1c = min(max(y1, 0), H - 1);
    int x0c = min(max(x0, 0), W - 1), x1c = min(max(x1, 0), W - 1);
    *(float4*)&pw[i * 4] = make_float4((1.f - wy) * (1.f - wx) * m * vy0 * vx0,
                                       (1.f - wy) * wx * m * vy0 * vx1,
                                       wy * (1.f - wx) * m * vy1 * vx0,
                                       wy * wx * m * vy1 * vx1);
    pa4[i * 4 + 0] = (ushort)((y0c << 6) + x0c);
    pa4[i * 4 + 1] = (ushort)((y0c << 6) + x1c);
    pa4[i * 4 + 2] = (ushort)((y1c << 6) + x0c);
    pa4[i * 4 + 3] = (ushort)((y1c << 6) + x1c);
  }
  __syncthreads();   // pw/pa visible; red reads done (vs may alias)

  // ===== Phase 2: deformable GEMM, 32x32x16, split-K =====
  int ms = wv & 3, ks = wv >> 2;
  int cq = t & 15, ps = t >> 4;           // 8-ch group, pixel (0..31)
  int c0s = cq * 8;

  f32x16 acc = {};

  for (int tap = 0; tap < 9; ++tap) {
    short* vbuf = vs + (tap & 1) * VSZ;

    // --- sample: 1 px x 8 ch per thread, 4 corner gathers of 16 B ---
    {
      int idx = (ps * 9 + tap) * 4;
      float4 wq = *(const float4*)&pw[idx];
      uint4 u00 = *(const uint4*)&xbB[(int)pa4[idx]     * CIN + c0s];
      uint4 u01 = *(const uint4*)&xbB[(int)pa4[idx + 1] * CIN + c0s];
      uint4 u10 = *(const uint4*)&xbB[(int)pa4[idx + 2] * CIN + c0s];
      uint4 u11 = *(const uint4*)&xbB[(int)pa4[idx + 3] * CIN + c0s];
      uint4 packed;
#pragma unroll
      for (int j = 0; j < 4; ++j) {
        unsigned ua = ((const unsigned*)&u00)[j];
        unsigned ub = ((const unsigned*)&u01)[j];
        unsigned uc = ((const unsigned*)&u10)[j];
        unsigned ud = ((const unsigned*)&u11)[j];
        float s0 = fmaf(wq.w, bf_lo(ud), fmaf(wq.z, bf_lo(uc),
                   fmaf(wq.y, bf_lo(ub), wq.x * bf_lo(ua))));
        float s1 = fmaf(wq.w, bf_hi(ud), fmaf(wq.z, bf_hi(uc),
                   fmaf(wq.y, bf_hi(ub), wq.x * bf_hi(ua))));
        __hip_bfloat162 h2 = __float22bfloat162_rn(make_float2(s0, s1));
        ((unsigned*)&packed)[j] = *(unsigned*)&h2;
      }
      *(uint4*)&vbuf[ps * AP + c0s] = packed;
    }

    // --- A frags: 4 k-steps, contiguous 1 KB wave loads ---
    bf16x8 af[4];
#pragma unroll
    for (int i = 0; i < 4; ++i) {
      int kstep = ks * 4 + i;
      af[i] = *(const bf16x8*)&wAs[(((tap * 8 + kstep) * 4 + ms) * 64 + lane) * 8];
    }
    __syncthreads();   // vbuf visible; other buffer free for tap+1

    // --- MFMA: 4 k-steps of 32x32x16 ---
#pragma unroll
    for (int i = 0; i < 4; ++i) {
      int kstep = ks * 4 + i;
      int c0 = kstep * 16 + g * 8;
      bf16x8 bfr = *(const bf16x8*)&vbuf[n32 * AP + c0];
      acc = __builtin_amdgcn_mfma_f32_32x32x16_bf16(af[i], bfr, acc, 0, 0, 0);
    }
  }

  // ===== epilogue: split-K reduce via redE, then store =====
  __syncthreads();   // all MFMA vs-reads done before redE aliases
  if (ks == 1) {
#pragma unroll
    for (int r = 0; r < 16; ++r) {
      int row = (r & 3) + 8 * (r >> 2) + 4 * g;
      redE[ms * (32 * 33) + row * 33 + n32] = acc[r];
    }
  }
  __syncthreads();
  if (ks == 0) {
#pragma unroll
    for (int r = 0; r < 16; ++r) {
      int row = (r & 3) + 8 * (r >> 2) + 4 * g;
      float v = acc[r] + redE[ms * (32 * 33) + row * 33 + n32];
      out[(size_t)(b * COUT + ms * 32 + row) * NPIX + pix0 + n32] = v;
    }
  }
}

// ---------------------------------------------------------------------------
extern "C" void kernel_launch(void* const* d_in, const int* in_sizes, int n_in,
                              void* d_out, int out_size, void* d_ws, size_t ws_size,
                              hipStream_t stream) {
  const float* x     = (const float*)d_in[0];
  const float* w_off = (const float*)d_in[1];
  const float* b_off = (const float*)d_in[2];
  const float* w_mod = (const float*)d_in[3];
  const float* b_mod = (const float*)d_in[4];
  const float* w_reg = (const float*)d_in[5];

  short* xbh  = (short*)d_ws;              // 4,194,304 bf16 (8 MB)
  short* wAs  = xbh + 4194304;             //   147,456 bf16 (32x32 swizzled)
  short* wOMs = wAs + 147456;              //    36,864 bf16 (32x32 swizzled)
  float* out  = (float*)d_out;

  k_prep<<<dim3(2768), 256, 0, stream>>>(x, xbh, w_off, w_mod, wOMs,
                                         w_reg, wAs);
  k_deform<<<dim3(NPIX / PXT * BATCH), 512, 0, stream>>>(
      xbh, wOMs, b_off, b_mod, wAs, out);
}